// Round 12
// baseline (110.157 us; speedup 1.0000x reference)
//
#include <hip/hip_runtime.h>
#include <hip/hip_bf16.h>
#include <math.h>

// Fused attention-gate, round 12: r4 chassis with 32-px tiles.
//   g = BN(in_g @ Wg); x = BN(in_x @ Wx); s = relu(g+x)
//   psi = sigmoid(BN(s @ Wp)); out = x * psi
// C'[f][px] = W^T . pix^T. W held in VGPR/AGPR (full K=256, both tensors).
// 32-px tiles halve per-tile overhead (2 barriers, epilogue, drain) per byte
// vs r4's 16-px, double MFMA per barrier interval and in-flight VMEM at the
// drain. Schedule/swizzle/store-fence pattern identical to r4 (WRITE must
// stay 65536KB exact). xT stored bf16 [32][136] (16B-aligned padded rows).

typedef __bf16 bf16x8 __attribute__((ext_vector_type(8)));
typedef float f32x4 __attribute__((ext_vector_type(4)));

__device__ __forceinline__ unsigned short f2bf(float f) {
  union { float f; unsigned u; } v; v.f = f;
  unsigned r = (v.u + 0x7fffu + ((v.u >> 16) & 1u)) >> 16;
  return (unsigned short)r;
}
__device__ __forceinline__ float bf2f(unsigned u) {
  union { unsigned u; float f; } v; v.u = u << 16; return v.f;
}
__device__ __forceinline__ bf16x8 cvt8(float4 a, float4 b) {
  bf16x8 r;
  r[0]=(__bf16)a.x; r[1]=(__bf16)a.y; r[2]=(__bf16)a.z; r[3]=(__bf16)a.w;
  r[4]=(__bf16)b.x; r[5]=(__bf16)b.y; r[6]=(__bf16)b.z; r[7]=(__bf16)b.w;
  return r;
}

// ---------------- pre-kernel: fold BN into weights, fragment-linear ----------------
// Wfrag layout: [ftile(8)][ksg(8)][lane(64)][slot(8)] bf16 (64KB per tensor)
__global__ __launch_bounds__(256) void fold_weights(
    const float* __restrict__ Wg, const float* __restrict__ bg,
    const float* __restrict__ gg, const float* __restrict__ beg,
    const float* __restrict__ mg, const float* __restrict__ vg,
    const float* __restrict__ Wx, const float* __restrict__ bx,
    const float* __restrict__ gx, const float* __restrict__ bex,
    const float* __restrict__ mx, const float* __restrict__ vx,
    const float* __restrict__ Wp, const float* __restrict__ bp,
    const float* __restrict__ gp, const float* __restrict__ bep,
    const float* __restrict__ mp, const float* __restrict__ vp,
    unsigned short* __restrict__ Bfg, unsigned short* __restrict__ Bfx,
    float* __restrict__ cg, float* __restrict__ cx,
    float* __restrict__ wps, float* __restrict__ cps) {
  int idx = blockIdx.x * 256 + threadIdx.x;  // 0..32767 = 256(c) * 128(f)
  int c = idx >> 7;    // Cin / k index
  int f = idx & 127;   // F index
  float ivg = gg[f] * rsqrtf(vg[f] + 1e-3f);
  float ivx = gx[f] * rsqrtf(vx[f] + 1e-3f);
  int ftile = f >> 4;
  int ksg = c >> 5;
  int lane = (((c >> 3) & 3) << 4) | (f & 15);
  int slot = c & 7;
  int off = ((ftile * 8 + ksg) * 64 + lane) * 8 + slot;
  Bfg[off] = f2bf(Wg[c * 128 + f] * ivg);
  Bfx[off] = f2bf(Wx[c * 128 + f] * ivx);
  if (idx < 128) {
    float ivg2 = gg[idx] * rsqrtf(vg[idx] + 1e-3f);
    float ivx2 = gx[idx] * rsqrtf(vx[idx] + 1e-3f);
    cg[idx] = bg[idx] * ivg2 + beg[idx] - mg[idx] * ivg2;
    cx[idx] = bx[idx] * ivx2 + bex[idx] - mx[idx] * ivx2;
    float ip = gp[0] * rsqrtf(vp[0] + 1e-3f);
    wps[idx] = Wp[idx] * ip;
    if (idx == 0) cps[0] = bp[0] * ip + bep[0] - mp[0] * ip;
  }
}

// ---------------- main fused kernel ----------------
// 512 threads = 8 waves; wave wid owns f-tile wid (16 f), W in registers.
// Each block: 4 consecutive 32-pixel tiles, 2 barriers per tile (r4 fence).
__global__ __launch_bounds__(512, 4) void attn_gate_main(
    const float* __restrict__ ing, const float* __restrict__ inx,
    const unsigned short* __restrict__ Wfg, const unsigned short* __restrict__ Wfx,
    const float* __restrict__ cgp, const float* __restrict__ cxp,
    const float* __restrict__ wpp, const float* __restrict__ cpp,
    float* __restrict__ out) {
  __shared__ __align__(16) short pixT[2][2][8192];     // [buf][ten][32px*256k] 64KB
  __shared__ __align__(16) unsigned short xT[32 * 136]; // bf16, 272B rows   8.5KB
  __shared__ __align__(16) float psum[32][8];           // [px][wave]          1KB

  const int tid = threadIdx.x;
  const int lane = tid & 63;
  const int wid = tid >> 6;        // f-tile of this wave
  const int l15 = lane & 15, l4 = lane >> 4;

  // ---- W fragments into registers (L2/L3-hot table) ----
  bf16x8 wfg[8], wfx[8];
  #pragma unroll
  for (int ksg = 0; ksg < 8; ++ksg) {
    const int off = ((wid * 8 + ksg) * 64 + lane) * 8;
    wfg[ksg] = *reinterpret_cast<const bf16x8*>(Wfg + off);
    wfx[ksg] = *reinterpret_cast<const bf16x8*>(Wfx + off);
  }
  const int fb = wid * 16 + l4 * 4;  // this lane's 4 consecutive f = fb+reg
  const f32x4 cgv = *reinterpret_cast<const f32x4*>(cgp + fb);
  const f32x4 cxv = *reinterpret_cast<const f32x4*>(cxp + fb);
  const f32x4 wpv = *reinterpret_cast<const f32x4*>(wpp + fb);
  const float cpsv = cpp[0];

  // staging geometry: thread covers row spx (0..31), 16B slots {sk, sk+16}
  const int spx = tid >> 4;
  const int sk = tid & 15;
  const int sw0 = (spx << 9) | ((sk ^ (spx & 7)) << 4);
  const int sw1 = (spx << 9) | (((sk + 16) ^ (spx & 7)) << 4);
  const long tile0 = (long)blockIdx.x * 4;            // 32-px tiles
  const float* gsrc = ing + (tile0 * 32 + spx) * 256 + sk * 8;
  const float* xsrc = inx + (tile0 * 32 + spx) * 256 + sk * 8;

  // ---- prologue: stage tile 0 ----
  {
    float4 g0 = *reinterpret_cast<const float4*>(gsrc);
    float4 g1 = *reinterpret_cast<const float4*>(gsrc + 4);
    float4 g2 = *reinterpret_cast<const float4*>(gsrc + 128);
    float4 g3 = *reinterpret_cast<const float4*>(gsrc + 132);
    float4 x0 = *reinterpret_cast<const float4*>(xsrc);
    float4 x1 = *reinterpret_cast<const float4*>(xsrc + 4);
    float4 x2 = *reinterpret_cast<const float4*>(xsrc + 128);
    float4 x3 = *reinterpret_cast<const float4*>(xsrc + 132);
    *reinterpret_cast<bf16x8*>((char*)&pixT[0][0][0] + sw0) = cvt8(g0, g1);
    *reinterpret_cast<bf16x8*>((char*)&pixT[0][0][0] + sw1) = cvt8(g2, g3);
    *reinterpret_cast<bf16x8*>((char*)&pixT[0][1][0] + sw0) = cvt8(x0, x1);
    *reinterpret_cast<bf16x8*>((char*)&pixT[0][1][0] + sw1) = cvt8(x2, x3);
  }
  __syncthreads();

  #pragma unroll
  for (int t = 0; t < 4; ++t) {
    const int buf = t & 1;
    // [1] issue next tile's global loads (hidden under this tile's compute)
    float4 pg0, pg1, pg2, pg3, px0, px1, px2, px3;
    if (t < 3) {
      const float* g_ = gsrc + (t + 1) * 8192;
      const float* x_ = xsrc + (t + 1) * 8192;
      pg0 = *reinterpret_cast<const float4*>(g_);
      pg1 = *reinterpret_cast<const float4*>(g_ + 4);
      pg2 = *reinterpret_cast<const float4*>(g_ + 128);
      pg3 = *reinterpret_cast<const float4*>(g_ + 132);
      px0 = *reinterpret_cast<const float4*>(x_);
      px1 = *reinterpret_cast<const float4*>(x_ + 4);
      px2 = *reinterpret_cast<const float4*>(x_ + 128);
      px3 = *reinterpret_cast<const float4*>(x_ + 132);
    }

    // [2] compute: 32 ds_read + 32 MFMA (2 px-fragments x 2 tensors x 8 ksg)
    f32x4 ag0 = {0.f,0.f,0.f,0.f}, ag1 = {0.f,0.f,0.f,0.f};
    f32x4 ax0 = {0.f,0.f,0.f,0.f}, ax1 = {0.f,0.f,0.f,0.f};
    #pragma unroll
    for (int ksg = 0; ksg < 8; ++ksg) {
      const int ra = (l15 << 9) | ((((ksg << 2) | l4) ^ (l15 & 7)) << 4);
      const char* bg = (const char*)&pixT[buf][0][0];
      const char* bx = (const char*)&pixT[buf][1][0];
      bf16x8 fg0 = *reinterpret_cast<const bf16x8*>(bg + ra);
      bf16x8 fg1 = *reinterpret_cast<const bf16x8*>(bg + ra + (16 << 9));
      bf16x8 fx0 = *reinterpret_cast<const bf16x8*>(bx + ra);
      bf16x8 fx1 = *reinterpret_cast<const bf16x8*>(bx + ra + (16 << 9));
      ag0 = __builtin_amdgcn_mfma_f32_16x16x32_bf16(wfg[ksg], fg0, ag0, 0, 0, 0);
      ag1 = __builtin_amdgcn_mfma_f32_16x16x32_bf16(wfg[ksg], fg1, ag1, 0, 0, 0);
      ax0 = __builtin_amdgcn_mfma_f32_16x16x32_bf16(wfx[ksg], fx0, ax0, 0, 0, 0);
      ax1 = __builtin_amdgcn_mfma_f32_16x16x32_bf16(wfx[ksg], fx1, ax1, 0, 0, 0);
    }

    // [3] epilogue: bias, relu(g+x), psi partials, xT (bf16) write
    // C/D layout: px = (lane&15) + 16*sub, f = fb + reg
    #pragma unroll
    for (int sub = 0; sub < 2; ++sub) {
      const f32x4 accg = sub ? ag1 : ag0;
      const f32x4 accx = sub ? ax1 : ax0;
      float part = 0.f;
      unsigned pk0, pk1;
      {
        float xv0 = accx[0] + cxv[0], xv1 = accx[1] + cxv[1];
        float xv2 = accx[2] + cxv[2], xv3 = accx[3] + cxv[3];
        float s0 = (accg[0] + cgv[0]) + xv0; s0 = s0 > 0.f ? s0 : 0.f;
        float s1 = (accg[1] + cgv[1]) + xv1; s1 = s1 > 0.f ? s1 : 0.f;
        float s2 = (accg[2] + cgv[2]) + xv2; s2 = s2 > 0.f ? s2 : 0.f;
        float s3 = (accg[3] + cgv[3]) + xv3; s3 = s3 > 0.f ? s3 : 0.f;
        part = s0 * wpv[0] + s1 * wpv[1] + s2 * wpv[2] + s3 * wpv[3];
        pk0 = (unsigned)f2bf(xv0) | ((unsigned)f2bf(xv1) << 16);
        pk1 = (unsigned)f2bf(xv2) | ((unsigned)f2bf(xv3) << 16);
      }
      part += __shfl_xor(part, 16);   // sum over the 4 l4-groups (16 f)
      part += __shfl_xor(part, 32);
      const int row = l15 + sub * 16;
      if (lane < 16) psum[row][wid] = part;
      uint2 pk = {pk0, pk1};
      *reinterpret_cast<uint2*>((char*)xT + row * 272 + (wid * 4 + l4) * 8) = pk;
    }

    // [4] barrier 1: publishes xT/psum (r4 fence pattern)
    __syncthreads();

    // [5] psi + coalesced store (full 64B lines; 4 rows x 512B per wave)
    {
      const int px = tid >> 4, c = tid & 15;
      const f32x4 pa = *reinterpret_cast<const f32x4*>(&psum[px][0]);
      const f32x4 pb = *reinterpret_cast<const f32x4*>(&psum[px][4]);
      const float z = pa[0] + pa[1] + pa[2] + pa[3]
                    + pb[0] + pb[1] + pb[2] + pb[3] + cpsv;
      const float psi = 1.f / (1.f + __expf(-z));
      const uint4 w = *reinterpret_cast<const uint4*>((const char*)xT + px * 272 + c * 16);
      float4 o0, o1;
      o0.x = bf2f(w.x & 0xffff) * psi; o0.y = bf2f(w.x >> 16) * psi;
      o0.z = bf2f(w.y & 0xffff) * psi; o0.w = bf2f(w.y >> 16) * psi;
      o1.x = bf2f(w.z & 0xffff) * psi; o1.y = bf2f(w.z >> 16) * psi;
      o1.z = bf2f(w.w & 0xffff) * psi; o1.w = bf2f(w.w >> 16) * psi;
      float* op = out + ((tile0 + t) * 32 + px) * 128 + c * 8;
      *reinterpret_cast<float4*>(op) = o0;
      *reinterpret_cast<float4*>(op + 4) = o1;
    }

    // [6] stage next tile + barrier 2 (r4 fence pattern)
    if (t < 3) {
      *reinterpret_cast<bf16x8*>((char*)&pixT[buf ^ 1][0][0] + sw0) = cvt8(pg0, pg1);
      *reinterpret_cast<bf16x8*>((char*)&pixT[buf ^ 1][0][0] + sw1) = cvt8(pg2, pg3);
      *reinterpret_cast<bf16x8*>((char*)&pixT[buf ^ 1][1][0] + sw0) = cvt8(px0, px1);
      *reinterpret_cast<bf16x8*>((char*)&pixT[buf ^ 1][1][0] + sw1) = cvt8(px2, px3);
      __syncthreads();
    }
  }
}

extern "C" void kernel_launch(void* const* d_in, const int* in_sizes, int n_in,
                              void* d_out, int out_size, void* d_ws, size_t ws_size,
                              hipStream_t stream) {
  const float* ing = (const float*)d_in[0];
  const float* inx = (const float*)d_in[1];
  char* ws = (char*)d_ws;
  unsigned short* Bfg = (unsigned short*)ws;                 // 64 KB
  unsigned short* Bfx = (unsigned short*)(ws + 65536);       // 64 KB
  float* cg  = (float*)(ws + 131072);                        // 512 B
  float* cx  = (float*)(ws + 131584);                        // 512 B
  float* wps = (float*)(ws + 132096);                        // 512 B
  float* cps = (float*)(ws + 132608);                        // 4 B

  fold_weights<<<128, 256, 0, stream>>>(
      (const float*)d_in[2],  (const float*)d_in[3],  (const float*)d_in[4],
      (const float*)d_in[5],  (const float*)d_in[6],  (const float*)d_in[7],
      (const float*)d_in[8],  (const float*)d_in[9],  (const float*)d_in[10],
      (const float*)d_in[11], (const float*)d_in[12], (const float*)d_in[13],
      (const float*)d_in[14], (const float*)d_in[15], (const float*)d_in[16],
      (const float*)d_in[17], (const float*)d_in[18], (const float*)d_in[19],
      Bfg, Bfx, cg, cx, wps, cps);

  const int npix = in_sizes[0] / 256;   // 131072
  const int ntiles = npix / 32;         // 4096 (32-px tiles)
  attn_gate_main<<<ntiles / 4, 512, 0, stream>>>(
      ing, inx, Bfg, Bfx, cg, cx, wps, cps, (float*)d_out);
}